// Round 1
// baseline (2293.937 us; speedup 1.0000x reference)
//
#include <hip/hip_runtime.h>
#include <hip/hip_bf16.h>

#define SLEN 1024
#define BSZ 32
#define NHEAD 16
#define DHEAD 64
#define INDIM 1024

typedef __attribute__((ext_vector_type(8))) __bf16 bf16x8;
typedef __attribute__((ext_vector_type(4))) float f32x4;

__device__ __forceinline__ float wave_reduce_sum(float v) {
#pragma unroll
  for (int s = 1; s < 64; s <<= 1) v += __shfl_xor(v, s, 64);
  return v;
}
__device__ __forceinline__ float wave_reduce_max(float v) {
#pragma unroll
  for (int s = 1; s < 64; s <<= 1) v = fmaxf(v, __shfl_xor(v, s, 64));
  return v;
}

// ---------------------------------------------------------------------------
// Scan kernel: one (b,head) pair per 256-thread block (4 waves).
// wave 0: Wy rows (lane l owns row l, 64 fp32 regs)
// wave 1: Wq rows ; wave 2: Wk rows
// wave 3: wb rows (lane d owns wb[d][0..3]) + beta + x prefetch
// ---------------------------------------------------------------------------
__global__ __launch_bounds__(256, 2) void srwm_scan(
    const float* __restrict__ h,
    const float* __restrict__ Wy0, const float* __restrict__ Wq0,
    const float* __restrict__ Wk0, const float* __restrict__ wb0,
    __hip_bfloat16* __restrict__ ys)
{
  const int p  = blockIdx.x;          // 0..511
  const int b  = p >> 4;
  const int hd = p & 15;
  const int tid = threadIdx.x;
  const int w = tid >> 6, l = tid & 63;

  __shared__ float sx[64];
  __shared__ float sq[64];
  __shared__ float sk[64];
  __shared__ float sbeta[4];

  float wrow[64];   // waves 0-2: full W row; wave 3: only [0..3] used (wb row)

  if (w == 0) {
    const float* s = Wy0 + hd * DHEAD * DHEAD + l * DHEAD;
#pragma unroll
    for (int d = 0; d < 64; ++d) wrow[d] = s[d];
  } else if (w == 1) {
    const float* s = Wq0 + hd * DHEAD * DHEAD + l * DHEAD;
#pragma unroll
    for (int d = 0; d < 64; ++d) wrow[d] = s[d];
  } else if (w == 2) {
    const float* s = Wk0 + hd * DHEAD * DHEAD + l * DHEAD;
#pragma unroll
    for (int d = 0; d < 64; ++d) wrow[d] = s[d];
  } else {
    const float* s = wb0 + hd * DHEAD * 4 + l * 4;
#pragma unroll
    for (int j = 0; j < 4; ++j) wrow[j] = s[j];
    // preload x_0
    sx[l] = h[(size_t)b * INDIM + hd * DHEAD + l];
  }
  __syncthreads();

  const size_t xstride = (size_t)BSZ * INDIM;
  const float* xbase = h + (size_t)b * INDIM + hd * DHEAD + l;
  __hip_bfloat16* ybase = ys + (size_t)b * INDIM + hd * DHEAD + l;

  float xnext = 0.f;

#pragma unroll 1
  for (int t = 0; t < SLEN; ++t) {
    // ---------------- Phase A: a = W @ x_t ; beta ; softmaxes ----------------
    if (w < 3) {
      float a = 0.f;
#pragma unroll
      for (int c = 0; c < 16; ++c) {
        const float4 xc = *(const float4*)(sx + 4 * c);   // broadcast read
        a = fmaf(wrow[4 * c + 0], xc.x, a);
        a = fmaf(wrow[4 * c + 1], xc.y, a);
        a = fmaf(wrow[4 * c + 2], xc.z, a);
        a = fmaf(wrow[4 * c + 3], xc.w, a);
      }
      const float mx = wave_reduce_max(a);
      const float e  = __expf(a - mx);
      const float se = wave_reduce_sum(e);
      const float sm = e / se;
      if (w == 0) {
        // out_t = softmax(y) -> bf16 store (feeds the projection GEMM)
        ybase[(size_t)t * xstride] = __float2bfloat16(sm);
      } else if (w == 1) {
        sq[l] = sm;
      } else {
        sk[l] = sm;
      }
    } else {
      // wave 3: prefetch x_{t+1}; beta = sigmoid(wb^T x)
      const int tn = (t + 1 < SLEN) ? (t + 1) : t;
      xnext = xbase[(size_t)tn * xstride];
      const float xd = sx[l];
      float z0 = wrow[0] * xd, z1 = wrow[1] * xd;
      float z2 = wrow[2] * xd, z3 = wrow[3] * xd;
      z0 = wave_reduce_sum(z0); z1 = wave_reduce_sum(z1);
      z2 = wave_reduce_sum(z2); z3 = wave_reduce_sum(z3);
      if (l == 0) {
        sbeta[0] = 1.f / (1.f + __expf(-z0));
        sbeta[1] = 1.f / (1.f + __expf(-z1));
        sbeta[2] = 1.f / (1.f + __expf(-z2));
        sbeta[3] = 1.f / (1.f + __expf(-z3));
      }
    }
    __syncthreads();   // barrier 1: q,k,beta visible

    // ---------------- Phase B+C: cross terms, rank-1 update ------------------
    if (w < 3) {
      float kreg[64];
#pragma unroll
      for (int c = 0; c < 16; ++c) {
        const float4 kc = *(const float4*)(sk + 4 * c);
        kreg[4 * c + 0] = kc.x; kreg[4 * c + 1] = kc.y;
        kreg[4 * c + 2] = kc.z; kreg[4 * c + 3] = kc.w;
      }
      float aq = 0.f, ak = 0.f;
#pragma unroll
      for (int c = 0; c < 16; ++c) {
        const float4 qc = *(const float4*)(sq + 4 * c);
        aq = fmaf(wrow[4 * c + 0], qc.x, aq);
        aq = fmaf(wrow[4 * c + 1], qc.y, aq);
        aq = fmaf(wrow[4 * c + 2], qc.z, aq);
        aq = fmaf(wrow[4 * c + 3], qc.w, aq);
      }
#pragma unroll
      for (int d = 0; d < 64; ++d) ak = fmaf(wrow[d], kreg[d], ak);
      const float sc = sbeta[w] * (aq - ak);
#pragma unroll
      for (int d = 0; d < 64; ++d) wrow[d] = fmaf(sc, kreg[d], wrow[d]);
    } else {
      const float qd = sq[l], kd = sk[l];
      float bq0 = wrow[0] * qd, bq1 = wrow[1] * qd;
      float bq2 = wrow[2] * qd, bq3 = wrow[3] * qd;
      float bk0 = wrow[0] * kd, bk1 = wrow[1] * kd;
      float bk2 = wrow[2] * kd, bk3 = wrow[3] * kd;
      bq0 = wave_reduce_sum(bq0); bq1 = wave_reduce_sum(bq1);
      bq2 = wave_reduce_sum(bq2); bq3 = wave_reduce_sum(bq3);
      bk0 = wave_reduce_sum(bk0); bk1 = wave_reduce_sum(bk1);
      bk2 = wave_reduce_sum(bk2); bk3 = wave_reduce_sum(bk3);
      const float b3 = sbeta[3];
      const float s3 = b3 * kd;
      wrow[0] = fmaf(s3, bq0 - bk0, wrow[0]);
      wrow[1] = fmaf(s3, bq1 - bk1, wrow[1]);
      wrow[2] = fmaf(s3, bq2 - bk2, wrow[2]);
      wrow[3] = fmaf(s3, bq3 - bk3, wrow[3]);
      // publish prefetched x_{t+1} (phase-A reads of x_t are done)
      sx[l] = xnext;
    }
    __syncthreads();   // barrier 2
  }
}

// ---------------------------------------------------------------------------
// LayerNorm row stats: mu, rsqrt(var+eps) per (t,b) row of h
// ---------------------------------------------------------------------------
__global__ __launch_bounds__(256) void ln_stats(
    const float* __restrict__ h, float2* __restrict__ stats)
{
  const int row = blockIdx.x * 4 + (threadIdx.x >> 6);
  const int l = threadIdx.x & 63;
  const float4* hp = (const float4*)(h + (size_t)row * INDIM);
  float s = 0.f, s2 = 0.f;
#pragma unroll
  for (int c = 0; c < 4; ++c) {
    const float4 v = hp[c * 64 + l];
    s  += v.x + v.y + v.z + v.w;
    s2 += v.x * v.x + v.y * v.y + v.z * v.z + v.w * v.w;
  }
  s  = wave_reduce_sum(s);
  s2 = wave_reduce_sum(s2);
  if (l == 0) {
    const float mu  = s * (1.f / INDIM);
    const float var = s2 * (1.f / INDIM) - mu * mu;
    stats[row] = make_float2(mu, rsqrtf(var + 1e-5f));
  }
}

// ---------------------------------------------------------------------------
// out_w fp32 -> bf16
// ---------------------------------------------------------------------------
__global__ void cvt_bf16(const float* __restrict__ src,
                         __hip_bfloat16* __restrict__ dst, int n)
{
  const int i = blockIdx.x * blockDim.x + threadIdx.x;
  if (i < n) dst[i] = __float2bfloat16(src[i]);
}

// ---------------------------------------------------------------------------
// C[m][n] = sum_k ys[m][k] * W[n][k]  (both K-major), fused LN + residual
// 128x128 tile, BK=32, 4 waves (2x2), each wave 64x64 via 4x4 16x16x32 MFMA
// ---------------------------------------------------------------------------
__global__ __launch_bounds__(256) void gemm_ln(
    const __hip_bfloat16* __restrict__ A,   // ys   (32768,1024)
    const __hip_bfloat16* __restrict__ Bw,  // w    (1024,1024)
    const float* __restrict__ h,
    const float2* __restrict__ stats,
    const float* __restrict__ g,
    const float* __restrict__ bvec,
    float* __restrict__ out)
{
  const int K = INDIM;
  __shared__ __align__(16) __hip_bfloat16 As[128 * 32];
  __shared__ __align__(16) __hip_bfloat16 Bs[128 * 32];
  const int tid = threadIdx.x, w = tid >> 6, l = tid & 63;
  const int wm = w >> 1, wn = w & 1;
  const int m0 = blockIdx.x * 128, n0 = blockIdx.y * 128;

  f32x4 acc[4][4];
#pragma unroll
  for (int i = 0; i < 4; ++i)
#pragma unroll
    for (int j = 0; j < 4; ++j) acc[i][j] = (f32x4)(0.f);

  const int mr = tid >> 2;            // staging row (0..63), pass1 adds 64
  const int kc = (tid & 3) * 8;       // k element offset within 32

  for (int k0 = 0; k0 < K; k0 += 32) {
    const uint4 va0 = *(const uint4*)(A  + (size_t)(m0 + mr)      * K + k0 + kc);
    const uint4 va1 = *(const uint4*)(A  + (size_t)(m0 + mr + 64) * K + k0 + kc);
    const uint4 vb0 = *(const uint4*)(Bw + (size_t)(n0 + mr)      * K + k0 + kc);
    const uint4 vb1 = *(const uint4*)(Bw + (size_t)(n0 + mr + 64) * K + k0 + kc);
    *(uint4*)((char*)As + (size_t)tid * 16)         = va0;
    *(uint4*)((char*)As + (size_t)(tid + 256) * 16) = va1;
    *(uint4*)((char*)Bs + (size_t)tid * 16)         = vb0;
    *(uint4*)((char*)Bs + (size_t)(tid + 256) * 16) = vb1;
    __syncthreads();

    bf16x8 af[4], bfr[4];
    const int koff = (l >> 4) * 16;   // byte offset of this lane's k-group
#pragma unroll
    for (int i = 0; i < 4; ++i) {
      af[i]  = *(const bf16x8*)((const char*)As +
                 (size_t)(wm * 64 + i * 16 + (l & 15)) * 64 + koff);
      bfr[i] = *(const bf16x8*)((const char*)Bs +
                 (size_t)(wn * 64 + i * 16 + (l & 15)) * 64 + koff);
    }
#pragma unroll
    for (int i = 0; i < 4; ++i)
#pragma unroll
      for (int j = 0; j < 4; ++j)
        acc[i][j] = __builtin_amdgcn_mfma_f32_16x16x32_bf16(
            af[i], bfr[j], acc[i][j], 0, 0, 0);
    __syncthreads();
  }

  // epilogue: out = acc + (h - mu)*rsig*g + b
  float gv[4], bv[4];
  int cols[4];
#pragma unroll
  for (int j = 0; j < 4; ++j) {
    const int col = n0 + wn * 64 + j * 16 + (l & 15);
    cols[j] = col; gv[j] = g[col]; bv[j] = bvec[col];
  }
#pragma unroll
  for (int i = 0; i < 4; ++i) {
#pragma unroll
    for (int r = 0; r < 4; ++r) {
      const int row = m0 + wm * 64 + i * 16 + (l >> 4) * 4 + r;
      const float2 st = stats[row];
      const float* hrow = h + (size_t)row * INDIM;
      float* orow = out + (size_t)row * INDIM;
#pragma unroll
      for (int j = 0; j < 4; ++j) {
        const float lnv = (hrow[cols[j]] - st.x) * st.y * gv[j] + bv[j];
        orow[cols[j]] = acc[i][j][r] + lnv;
      }
    }
  }
}

extern "C" void kernel_launch(void* const* d_in, const int* in_sizes, int n_in,
                              void* d_out, int out_size, void* d_ws, size_t ws_size,
                              hipStream_t stream)
{
  const float* h    = (const float*)d_in[0];
  const float* Wy   = (const float*)d_in[1];
  const float* Wq   = (const float*)d_in[2];
  const float* Wk   = (const float*)d_in[3];
  const float* wb   = (const float*)d_in[4];
  const float* outw = (const float*)d_in[5];
  const float* lng  = (const float*)d_in[6];
  const float* lnb  = (const float*)d_in[7];
  float* out = (float*)d_out;

  char* ws = (char*)d_ws;
  __hip_bfloat16* ys  = (__hip_bfloat16*)ws;                       // 67,108,864 B
  __hip_bfloat16* wbf = (__hip_bfloat16*)(ws + 67108864);          //  2,097,152 B
  float2*       stats = (float2*)(ws + 67108864 + 2097152);        //    262,144 B

  cvt_bf16 <<<4096, 256, 0, stream>>>(outw, wbf, INDIM * INDIM);
  ln_stats <<<8192, 256, 0, stream>>>(h, stats);
  srwm_scan<<<512,  256, 0, stream>>>(h, Wy, Wq, Wk, wb, ys);
  gemm_ln  <<<dim3(256, 8), 256, 0, stream>>>(ys, wbf, h, stats, lng, lnb, out);
}

// Round 2
// 2012.678 us; speedup vs baseline: 1.1397x; 1.1397x over previous
//
#include <hip/hip_runtime.h>
#include <hip/hip_bf16.h>

#define SLEN 1024
#define BSZ 32
#define NHEAD 16
#define DHEAD 64
#define INDIM 1024

typedef __attribute__((ext_vector_type(8))) __bf16 bf16x8;
typedef __attribute__((ext_vector_type(4))) float f32x4;

// ---------------------------------------------------------------------------
// DPP-based wave-64 reductions (pure VALU, ~6 dependent stages).
// Result is made wave-uniform via readlane(63).
// ---------------------------------------------------------------------------
template <int C>
__device__ __forceinline__ float dppmov(float v) {
  return __int_as_float(__builtin_amdgcn_update_dpp(
      __float_as_int(v), __float_as_int(v), C, 0xF, 0xF, false));
}
__device__ __forceinline__ float wred_sum_u(float v) {
  v += dppmov<0x111>(v);   // row_shr:1
  v += dppmov<0x112>(v);   // row_shr:2
  v += dppmov<0x114>(v);   // row_shr:4
  v += dppmov<0x118>(v);   // row_shr:8
  v += dppmov<0x142>(v);   // row_bcast:15
  v += dppmov<0x143>(v);   // row_bcast:31
  return __int_as_float(__builtin_amdgcn_readlane(__float_as_int(v), 63));
}
__device__ __forceinline__ float wred_max_u(float v) {
  v = fmaxf(v, dppmov<0x111>(v));
  v = fmaxf(v, dppmov<0x112>(v));
  v = fmaxf(v, dppmov<0x114>(v));
  v = fmaxf(v, dppmov<0x118>(v));
  v = fmaxf(v, dppmov<0x142>(v));
  v = fmaxf(v, dppmov<0x143>(v));
  return __int_as_float(__builtin_amdgcn_readlane(__float_as_int(v), 63));
}

// ---------------------------------------------------------------------------
// Scan kernel: one (b,head) pair per 256-thread block (4 waves).
// waves 0-2: lane l owns row l of Wy/Wq/Wk (64 fp32 regs)
// wave 3: lane d owns wb[d][0..3]; computes beta; manages x double-buffer
// One __syncthreads per step (sx/sq/sk/sbeta double-buffered).
// ---------------------------------------------------------------------------
__global__ __launch_bounds__(256, 2) void srwm_scan(
    const float* __restrict__ h,
    const float* __restrict__ Wy0, const float* __restrict__ Wq0,
    const float* __restrict__ Wk0, const float* __restrict__ wb0,
    __hip_bfloat16* __restrict__ ys)
{
  const int p  = blockIdx.x;          // 0..511
  const int b  = p >> 4;
  const int hd = p & 15;
  const int tid = threadIdx.x;
  const int w = tid >> 6, l = tid & 63;

  __shared__ float sx[2][64];
  __shared__ float sq[2][64];
  __shared__ float sk[2][64];
  __shared__ float sbeta[2][4];

  float wrow[64];   // waves 0-2: full W row; wave 3: only [0..3] used (wb row)
  float xnext = 0.f;

  if (w == 0) {
    const float* s = Wy0 + (hd * DHEAD + l) * DHEAD;
#pragma unroll
    for (int d = 0; d < 64; ++d) wrow[d] = s[d];
  } else if (w == 1) {
    const float* s = Wq0 + (hd * DHEAD + l) * DHEAD;
#pragma unroll
    for (int d = 0; d < 64; ++d) wrow[d] = s[d];
  } else if (w == 2) {
    const float* s = Wk0 + (hd * DHEAD + l) * DHEAD;
#pragma unroll
    for (int d = 0; d < 64; ++d) wrow[d] = s[d];
  } else {
    const float* s = wb0 + (hd * DHEAD + l) * 4;
#pragma unroll
    for (int j = 0; j < 4; ++j) wrow[j] = s[j];
    // x_0 into buffer 0, x_1 prefetched into xnext
    sx[0][l] = h[(size_t)b * INDIM + hd * DHEAD + l];
    xnext = h[(size_t)BSZ * INDIM + (size_t)b * INDIM + hd * DHEAD + l];
  }
  __syncthreads();

  const size_t xstride = (size_t)BSZ * INDIM;
  const float* xsrc = h + (size_t)b * INDIM + hd * DHEAD + l;
  __hip_bfloat16* ydst = ys + (size_t)b * INDIM + hd * DHEAD + l;

#pragma unroll 2
  for (int t = 0; t < SLEN; ++t) {
    const int cur = t & 1, nxt = cur ^ 1;
    // ---------------- Phase A ----------------
    if (w < 3) {
      const float* xb = sx[cur];
      float a0 = 0.f, a1 = 0.f, a2 = 0.f, a3 = 0.f;
#pragma unroll
      for (int c = 0; c < 16; ++c) {
        const float4 xc = *(const float4*)(xb + 4 * c);   // broadcast read
        a0 = fmaf(wrow[4 * c + 0], xc.x, a0);
        a1 = fmaf(wrow[4 * c + 1], xc.y, a1);
        a2 = fmaf(wrow[4 * c + 2], xc.z, a2);
        a3 = fmaf(wrow[4 * c + 3], xc.w, a3);
      }
      const float a = (a0 + a1) + (a2 + a3);
      const float m = wred_max_u(a);
      const float e = __expf(a - m);
      const float s = wred_sum_u(e);
      const float sm = e * __builtin_amdgcn_rcpf(s);
      if (w == 0) {
        ydst[(size_t)t * xstride] = __float2bfloat16(sm);
      } else if (w == 1) {
        sq[cur][l] = sm;
      } else {
        sk[cur][l] = sm;
      }
    } else {
      // publish x_{t+1} (loaded last step), issue load of x_{t+2}
      sx[nxt][l] = xnext;
      const int tload = (t + 2 < SLEN) ? (t + 2) : (SLEN - 1);
      xnext = xsrc[(size_t)tload * xstride];
      // beta = sigmoid(wb^T x_t): 4 independent DPP reduction chains
      const float xd = sx[cur][l];
      const float z0 = wred_sum_u(wrow[0] * xd);
      const float z1 = wred_sum_u(wrow[1] * xd);
      const float z2 = wred_sum_u(wrow[2] * xd);
      const float z3 = wred_sum_u(wrow[3] * xd);
      if (l == 0) {
        sbeta[cur][0] = __builtin_amdgcn_rcpf(1.f + __expf(-z0));
        sbeta[cur][1] = __builtin_amdgcn_rcpf(1.f + __expf(-z1));
        sbeta[cur][2] = __builtin_amdgcn_rcpf(1.f + __expf(-z2));
        sbeta[cur][3] = __builtin_amdgcn_rcpf(1.f + __expf(-z3));
      }
    }
    __syncthreads();   // the only barrier per step
    // ---------------- Phase B ----------------
    if (w < 3) {
      const float* qb = sq[cur];
      const float* kb = sk[cur];
      const float beta = sbeta[cur][w];
      float4 kreg[16];
      float d0 = 0.f, d1 = 0.f, d2 = 0.f, d3 = 0.f;
#pragma unroll
      for (int c = 0; c < 16; ++c) {
        const float4 qc = *(const float4*)(qb + 4 * c);
        const float4 kc = *(const float4*)(kb + 4 * c);
        kreg[c] = kc;
        d0 = fmaf(wrow[4 * c + 0], qc.x - kc.x, d0);
        d1 = fmaf(wrow[4 * c + 1], qc.y - kc.y, d1);
        d2 = fmaf(wrow[4 * c + 2], qc.z - kc.z, d2);
        d3 = fmaf(wrow[4 * c + 3], qc.w - kc.w, d3);
      }
      const float sc = beta * ((d0 + d1) + (d2 + d3));
#pragma unroll
      for (int c = 0; c < 16; ++c) {
        wrow[4 * c + 0] = fmaf(sc, kreg[c].x, wrow[4 * c + 0]);
        wrow[4 * c + 1] = fmaf(sc, kreg[c].y, wrow[4 * c + 1]);
        wrow[4 * c + 2] = fmaf(sc, kreg[c].z, wrow[4 * c + 2]);
        wrow[4 * c + 3] = fmaf(sc, kreg[c].w, wrow[4 * c + 3]);
      }
    } else {
      // wb update: wb[l][j] += beta3 * k_l * (bq_j - bk_j),  bq-bk = wb^T(q-k)
      const float qd = sq[cur][l], kd = sk[cur][l];
      const float dd = qd - kd;
      const float z0 = wred_sum_u(wrow[0] * dd);
      const float z1 = wred_sum_u(wrow[1] * dd);
      const float z2 = wred_sum_u(wrow[2] * dd);
      const float z3 = wred_sum_u(wrow[3] * dd);
      const float s3 = sbeta[cur][3] * kd;
      wrow[0] = fmaf(s3, z0, wrow[0]);
      wrow[1] = fmaf(s3, z1, wrow[1]);
      wrow[2] = fmaf(s3, z2, wrow[2]);
      wrow[3] = fmaf(s3, z3, wrow[3]);
    }
    // no second barrier: buffers double-buffered, next write to any location
    // read in phase B(t) is separated by the barrier of step t+1
  }
}

// ---------------------------------------------------------------------------
// LayerNorm row stats: mu, rsqrt(var+eps) per (t,b) row of h
// ---------------------------------------------------------------------------
__global__ __launch_bounds__(256) void ln_stats(
    const float* __restrict__ h, float2* __restrict__ stats)
{
  const int row = blockIdx.x * 4 + (threadIdx.x >> 6);
  const int l = threadIdx.x & 63;
  const float4* hp = (const float4*)(h + (size_t)row * INDIM);
  float s = 0.f, s2 = 0.f;
#pragma unroll
  for (int c = 0; c < 4; ++c) {
    const float4 v = hp[c * 64 + l];
    s  += v.x + v.y + v.z + v.w;
    s2 += v.x * v.x + v.y * v.y + v.z * v.z + v.w * v.w;
  }
  s  = wred_sum_u(s);
  s2 = wred_sum_u(s2);
  if (l == 0) {
    const float mu  = s * (1.f / INDIM);
    const float var = s2 * (1.f / INDIM) - mu * mu;
    stats[row] = make_float2(mu, rsqrtf(var + 1e-5f));
  }
}

// ---------------------------------------------------------------------------
// out_w fp32 -> bf16
// ---------------------------------------------------------------------------
__global__ void cvt_bf16(const float* __restrict__ src,
                         __hip_bfloat16* __restrict__ dst, int n)
{
  const int i = blockIdx.x * blockDim.x + threadIdx.x;
  if (i < n) dst[i] = __float2bfloat16(src[i]);
}

// ---------------------------------------------------------------------------
// C[m][n] = sum_k ys[m][k] * W[n][k]  (both K-major), fused LN + residual
// 128x128 tile, BK=32, 4 waves (2x2), each wave 64x64 via 4x4 16x16x32 MFMA
// ---------------------------------------------------------------------------
__global__ __launch_bounds__(256) void gemm_ln(
    const __hip_bfloat16* __restrict__ A,   // ys   (32768,1024)
    const __hip_bfloat16* __restrict__ Bw,  // w    (1024,1024)
    const float* __restrict__ h,
    const float2* __restrict__ stats,
    const float* __restrict__ g,
    const float* __restrict__ bvec,
    float* __restrict__ out)
{
  const int K = INDIM;
  __shared__ __align__(16) __hip_bfloat16 As[128 * 32];
  __shared__ __align__(16) __hip_bfloat16 Bs[128 * 32];
  const int tid = threadIdx.x, w = tid >> 6, l = tid & 63;
  const int wm = w >> 1, wn = w & 1;
  const int m0 = blockIdx.x * 128, n0 = blockIdx.y * 128;

  f32x4 acc[4][4];
#pragma unroll
  for (int i = 0; i < 4; ++i)
#pragma unroll
    for (int j = 0; j < 4; ++j) acc[i][j] = (f32x4)(0.f);

  const int mr = tid >> 2;            // staging row (0..63), pass1 adds 64
  const int kc = (tid & 3) * 8;       // k element offset within 32

  for (int k0 = 0; k0 < K; k0 += 32) {
    const uint4 va0 = *(const uint4*)(A  + (size_t)(m0 + mr)      * K + k0 + kc);
    const uint4 va1 = *(const uint4*)(A  + (size_t)(m0 + mr + 64) * K + k0 + kc);
    const uint4 vb0 = *(const uint4*)(Bw + (size_t)(n0 + mr)      * K + k0 + kc);
    const uint4 vb1 = *(const uint4*)(Bw + (size_t)(n0 + mr + 64) * K + k0 + kc);
    *(uint4*)((char*)As + (size_t)tid * 16)         = va0;
    *(uint4*)((char*)As + (size_t)(tid + 256) * 16) = va1;
    *(uint4*)((char*)Bs + (size_t)tid * 16)         = vb0;
    *(uint4*)((char*)Bs + (size_t)(tid + 256) * 16) = vb1;
    __syncthreads();

    bf16x8 af[4], bfr[4];
    const int koff = (l >> 4) * 16;   // byte offset of this lane's k-group
#pragma unroll
    for (int i = 0; i < 4; ++i) {
      af[i]  = *(const bf16x8*)((const char*)As +
                 (size_t)(wm * 64 + i * 16 + (l & 15)) * 64 + koff);
      bfr[i] = *(const bf16x8*)((const char*)Bs +
                 (size_t)(wn * 64 + i * 16 + (l & 15)) * 64 + koff);
    }
#pragma unroll
    for (int i = 0; i < 4; ++i)
#pragma unroll
      for (int j = 0; j < 4; ++j)
        acc[i][j] = __builtin_amdgcn_mfma_f32_16x16x32_bf16(
            af[i], bfr[j], acc[i][j], 0, 0, 0);
    __syncthreads();
  }

  // epilogue: out = acc + (h - mu)*rsig*g + b
  float gv[4], bv[4];
  int cols[4];
#pragma unroll
  for (int j = 0; j < 4; ++j) {
    const int col = n0 + wn * 64 + j * 16 + (l & 15);
    cols[j] = col; gv[j] = g[col]; bv[j] = bvec[col];
  }
#pragma unroll
  for (int i = 0; i < 4; ++i) {
#pragma unroll
    for (int r = 0; r < 4; ++r) {
      const int row = m0 + wm * 64 + i * 16 + (l >> 4) * 4 + r;
      const float2 st = stats[row];
      const float* hrow = h + (size_t)row * INDIM;
      float* orow = out + (size_t)row * INDIM;
#pragma unroll
      for (int j = 0; j < 4; ++j) {
        const float lnv = (hrow[cols[j]] - st.x) * st.y * gv[j] + bv[j];
        orow[cols[j]] = acc[i][j][r] + lnv;
      }
    }
  }
}

extern "C" void kernel_launch(void* const* d_in, const int* in_sizes, int n_in,
                              void* d_out, int out_size, void* d_ws, size_t ws_size,
                              hipStream_t stream)
{
  const float* h    = (const float*)d_in[0];
  const float* Wy   = (const float*)d_in[1];
  const float* Wq   = (const float*)d_in[2];
  const float* Wk   = (const float*)d_in[3];
  const float* wb   = (const float*)d_in[4];
  const float* outw = (const float*)d_in[5];
  const float* lng  = (const float*)d_in[6];
  const float* lnb  = (const float*)d_in[7];
  float* out = (float*)d_out;

  char* ws = (char*)d_ws;
  __hip_bfloat16* ys  = (__hip_bfloat16*)ws;                       // 67,108,864 B
  __hip_bfloat16* wbf = (__hip_bfloat16*)(ws + 67108864);          //  2,097,152 B
  float2*       stats = (float2*)(ws + 67108864 + 2097152);        //    262,144 B

  cvt_bf16 <<<4096, 256, 0, stream>>>(outw, wbf, INDIM * INDIM);
  ln_stats <<<8192, 256, 0, stream>>>(h, stats);
  srwm_scan<<<512,  256, 0, stream>>>(h, Wy, Wq, Wk, wb, ys);
  gemm_ln  <<<dim3(256, 8), 256, 0, stream>>>(ys, wbf, h, stats, lng, lnb, out);
}

// Round 3
// 1598.732 us; speedup vs baseline: 1.4348x; 1.2589x over previous
//
#include <hip/hip_runtime.h>
#include <hip/hip_bf16.h>

#define SLEN 1024
#define BSZ 32
#define NHEAD 16
#define DHEAD 64
#define INDIM 1024

typedef __attribute__((ext_vector_type(8))) __bf16 bf16x8;
typedef __attribute__((ext_vector_type(4))) float f32x4;
typedef __attribute__((ext_vector_type(2))) float f32x2;

#if __has_builtin(__builtin_elementwise_fma)
__device__ __forceinline__ f32x2 pk_fma(f32x2 a, f32x2 b, f32x2 c) {
  return __builtin_elementwise_fma(a, b, c);
}
#else
__device__ __forceinline__ f32x2 pk_fma(f32x2 a, f32x2 b, f32x2 c) {
  f32x2 r; r.x = fmaf(a.x, b.x, c.x); r.y = fmaf(a.y, b.y, c.y); return r;
}
#endif

// ---------------------------------------------------------------------------
// DPP-based wave-64 reductions (pure VALU, 6 dependent stages).
// ---------------------------------------------------------------------------
template <int C>
__device__ __forceinline__ float dppmov(float v) {
  return __int_as_float(__builtin_amdgcn_update_dpp(
      __float_as_int(v), __float_as_int(v), C, 0xF, 0xF, false));
}
__device__ __forceinline__ float wred_sum_u(float v) {
  v += dppmov<0x111>(v);   // row_shr:1
  v += dppmov<0x112>(v);   // row_shr:2
  v += dppmov<0x114>(v);   // row_shr:4
  v += dppmov<0x118>(v);   // row_shr:8
  v += dppmov<0x142>(v);   // row_bcast:15
  v += dppmov<0x143>(v);   // row_bcast:31
  return __int_as_float(__builtin_amdgcn_readlane(__float_as_int(v), 63));
}
__device__ __forceinline__ float wred_max_u(float v) {
  v = fmaxf(v, dppmov<0x111>(v));
  v = fmaxf(v, dppmov<0x112>(v));
  v = fmaxf(v, dppmov<0x114>(v));
  v = fmaxf(v, dppmov<0x118>(v));
  v = fmaxf(v, dppmov<0x142>(v));
  v = fmaxf(v, dppmov<0x143>(v));
  return __int_as_float(__builtin_amdgcn_readlane(__float_as_int(v), 63));
}

// ---------------------------------------------------------------------------
// Scan kernel: one (b,head) pair per 256-thread block (4 waves).
// waves 0-2: lane l owns row l of Wy/Wq/Wk as 32 f32x2 (packed-fp32 math)
// wave 3: lane d owns wb[d][0..3]; computes beta; manages x double-buffer
// One __syncthreads per step. Softmax uses deferred (previous-step) shift:
// softmax is invariant to any wave-uniform shift, so the max-reduce chain
// runs OFF the critical path (only feeds the next step's shift).
// ---------------------------------------------------------------------------
__global__ __launch_bounds__(256, 2) void srwm_scan(
    const float* __restrict__ h,
    const float* __restrict__ Wy0, const float* __restrict__ Wq0,
    const float* __restrict__ Wk0, const float* __restrict__ wb0,
    __hip_bfloat16* __restrict__ ys)
{
  const int p  = blockIdx.x;          // 0..511
  const int b  = p >> 4;
  const int hd = p & 15;
  const int tid = threadIdx.x;
  const int w = tid >> 6, l = tid & 63;

  __shared__ float sx[2][64];
  __shared__ float sq[2][64];
  __shared__ float sk[2][64];
  __shared__ float sbeta[2][4];

  f32x2 wrow[32];   // waves 0-2: full W row; wave 3: [0..1] = wb row (4 vals)
  float xnext = 0.f;
  float cshift = 0.f;   // deferred softmax shift (wave-uniform)

  if (w < 3) {
    const float* base = (w == 0) ? Wy0 : (w == 1) ? Wq0 : Wk0;
    const float4* s4 = (const float4*)(base + (size_t)(hd * DHEAD + l) * DHEAD);
#pragma unroll
    for (int c = 0; c < 16; ++c) {
      const float4 v = s4[c];
      wrow[2 * c + 0] = f32x2{v.x, v.y};
      wrow[2 * c + 1] = f32x2{v.z, v.w};
    }
  } else {
    const float4 v = *(const float4*)(wb0 + (size_t)(hd * DHEAD + l) * 4);
    wrow[0] = f32x2{v.x, v.y};
    wrow[1] = f32x2{v.z, v.w};
    // x_0 into buffer 0, x_1 prefetched into xnext
    sx[0][l] = h[(size_t)b * INDIM + hd * DHEAD + l];
    xnext = h[(size_t)BSZ * INDIM + (size_t)b * INDIM + hd * DHEAD + l];
  }
  __syncthreads();

  const size_t xstride = (size_t)BSZ * INDIM;
  const float* xsrc = h + (size_t)b * INDIM + hd * DHEAD + l;
  __hip_bfloat16* ydst = ys + (size_t)b * INDIM + hd * DHEAD + l;

#pragma unroll 2
  for (int t = 0; t < SLEN; ++t) {
    const int cur = t & 1, nxt = cur ^ 1;
    // ---------------- Phase A ----------------
    if (w < 3) {
      const float* xb = sx[cur];
      f32x2 a0 = (f32x2)(0.f), a1 = (f32x2)(0.f);
#pragma unroll
      for (int c = 0; c < 16; ++c) {
        const float4 xc = *(const float4*)(xb + 4 * c);   // broadcast read
        a0 = pk_fma(wrow[2 * c + 0], f32x2{xc.x, xc.y}, a0);
        a1 = pk_fma(wrow[2 * c + 1], f32x2{xc.z, xc.w}, a1);
      }
      const f32x2 as = a0 + a1;
      const float a = as.x + as.y;
      // exp with deferred shift -> exact softmax, max-chain off critical path
      const float e = __expf(a - cshift);
      const float mnew = wred_max_u(a);      // independent, overlaps sum chain
      const float s = wred_sum_u(e);
      const float sm = e * __builtin_amdgcn_rcpf(s);
      cshift = mnew;
      if (w == 0) {
        ydst[(size_t)t * xstride] = __float2bfloat16(sm);
      } else if (w == 1) {
        sq[cur][l] = sm;
      } else {
        sk[cur][l] = sm;
      }
    } else {
      // publish x_{t+1} (loaded last step), issue load of x_{t+2}
      sx[nxt][l] = xnext;
      const int tload = (t + 2 < SLEN) ? (t + 2) : (SLEN - 1);
      xnext = xsrc[(size_t)tload * xstride];
      // beta = sigmoid(wb^T x_t): 4 independent DPP reduction chains
      const float xd = sx[cur][l];
      const float z0 = wred_sum_u(wrow[0].x * xd);
      const float z1 = wred_sum_u(wrow[0].y * xd);
      const float z2 = wred_sum_u(wrow[1].x * xd);
      const float z3 = wred_sum_u(wrow[1].y * xd);
      if (l == 0) {
        sbeta[cur][0] = __builtin_amdgcn_rcpf(1.f + __expf(-z0));
        sbeta[cur][1] = __builtin_amdgcn_rcpf(1.f + __expf(-z1));
        sbeta[cur][2] = __builtin_amdgcn_rcpf(1.f + __expf(-z2));
        sbeta[cur][3] = __builtin_amdgcn_rcpf(1.f + __expf(-z3));
      }
    }
    __syncthreads();   // the only barrier per step
    // ---------------- Phase B ----------------
    if (w < 3) {
      const float* qb = sq[cur];
      const float* kb = sk[cur];
      const float beta = sbeta[cur][w];
      f32x2 kr[32];                       // register-resident k
      f32x2 d0 = (f32x2)(0.f), d1 = (f32x2)(0.f);
#pragma unroll
      for (int c = 0; c < 16; ++c) {
        const float4 q4 = *(const float4*)(qb + 4 * c);
        const float4 k4 = *(const float4*)(kb + 4 * c);
        const f32x2 klo = f32x2{k4.x, k4.y}, khi = f32x2{k4.z, k4.w};
        kr[2 * c + 0] = klo; kr[2 * c + 1] = khi;
        d0 = pk_fma(wrow[2 * c + 0], f32x2{q4.x, q4.y} - klo, d0);
        d1 = pk_fma(wrow[2 * c + 1], f32x2{q4.z, q4.w} - khi, d1);
      }
      const f32x2 dsum = d0 + d1;
      const float sc = beta * (dsum.x + dsum.y);
      const f32x2 scv = (f32x2)(sc);
#pragma unroll
      for (int c = 0; c < 32; ++c) wrow[c] = pk_fma(scv, kr[c], wrow[c]);
    } else {
      // wb update: wb[l][j] += beta3 * k_l * (bq_j - bk_j),  bq-bk = wb^T(q-k)
      const float qd = sq[cur][l], kd = sk[cur][l];
      const float dd = qd - kd;
      const float z0 = wred_sum_u(wrow[0].x * dd);
      const float z1 = wred_sum_u(wrow[0].y * dd);
      const float z2 = wred_sum_u(wrow[1].x * dd);
      const float z3 = wred_sum_u(wrow[1].y * dd);
      const float s3 = sbeta[cur][3] * kd;
      wrow[0].x = fmaf(s3, z0, wrow[0].x);
      wrow[0].y = fmaf(s3, z1, wrow[0].y);
      wrow[1].x = fmaf(s3, z2, wrow[1].x);
      wrow[1].y = fmaf(s3, z3, wrow[1].y);
    }
    // no second barrier: buffers double-buffered; any cross-step reuse is
    // separated by the (single) barrier of the next step
  }
}

// ---------------------------------------------------------------------------
// LayerNorm row stats: mu, rsqrt(var+eps) per (t,b) row of h
// ---------------------------------------------------------------------------
__global__ __launch_bounds__(256) void ln_stats(
    const float* __restrict__ h, float2* __restrict__ stats)
{
  const int row = blockIdx.x * 4 + (threadIdx.x >> 6);
  const int l = threadIdx.x & 63;
  const float4* hp = (const float4*)(h + (size_t)row * INDIM);
  float s = 0.f, s2 = 0.f;
#pragma unroll
  for (int c = 0; c < 4; ++c) {
    const float4 v = hp[c * 64 + l];
    s  += v.x + v.y + v.z + v.w;
    s2 += v.x * v.x + v.y * v.y + v.z * v.z + v.w * v.w;
  }
  s  = wred_sum_u(s);
  s2 = wred_sum_u(s2);
  if (l == 0) {
    const float mu  = s * (1.f / INDIM);
    const float var = s2 * (1.f / INDIM) - mu * mu;
    stats[row] = make_float2(mu, rsqrtf(var + 1e-5f));
  }
}

// ---------------------------------------------------------------------------
// out_w fp32 -> bf16
// ---------------------------------------------------------------------------
__global__ void cvt_bf16(const float* __restrict__ src,
                         __hip_bfloat16* __restrict__ dst, int n)
{
  const int i = blockIdx.x * blockDim.x + threadIdx.x;
  if (i < n) dst[i] = __float2bfloat16(src[i]);
}

// ---------------------------------------------------------------------------
// C[m][n] = sum_k ys[m][k] * W[n][k]  (both K-major), fused LN + residual
// 128x128 tile, BK=32, 4 waves (2x2), each wave 64x64 via 4x4 16x16x32 MFMA
// ---------------------------------------------------------------------------
__global__ __launch_bounds__(256) void gemm_ln(
    const __hip_bfloat16* __restrict__ A,   // ys   (32768,1024)
    const __hip_bfloat16* __restrict__ Bw,  // w    (1024,1024)
    const float* __restrict__ h,
    const float2* __restrict__ stats,
    const float* __restrict__ g,
    const float* __restrict__ bvec,
    float* __restrict__ out)
{
  const int K = INDIM;
  __shared__ __align__(16) __hip_bfloat16 As[128 * 32];
  __shared__ __align__(16) __hip_bfloat16 Bs[128 * 32];
  const int tid = threadIdx.x, w = tid >> 6, l = tid & 63;
  const int wm = w >> 1, wn = w & 1;
  const int m0 = blockIdx.x * 128, n0 = blockIdx.y * 128;

  f32x4 acc[4][4];
#pragma unroll
  for (int i = 0; i < 4; ++i)
#pragma unroll
    for (int j = 0; j < 4; ++j) acc[i][j] = (f32x4)(0.f);

  const int mr = tid >> 2;            // staging row (0..63), pass1 adds 64
  const int kc = (tid & 3) * 8;       // k element offset within 32

  for (int k0 = 0; k0 < K; k0 += 32) {
    const uint4 va0 = *(const uint4*)(A  + (size_t)(m0 + mr)      * K + k0 + kc);
    const uint4 va1 = *(const uint4*)(A  + (size_t)(m0 + mr + 64) * K + k0 + kc);
    const uint4 vb0 = *(const uint4*)(Bw + (size_t)(n0 + mr)      * K + k0 + kc);
    const uint4 vb1 = *(const uint4*)(Bw + (size_t)(n0 + mr + 64) * K + k0 + kc);
    *(uint4*)((char*)As + (size_t)tid * 16)         = va0;
    *(uint4*)((char*)As + (size_t)(tid + 256) * 16) = va1;
    *(uint4*)((char*)Bs + (size_t)tid * 16)         = vb0;
    *(uint4*)((char*)Bs + (size_t)(tid + 256) * 16) = vb1;
    __syncthreads();

    bf16x8 af[4], bfr[4];
    const int koff = (l >> 4) * 16;   // byte offset of this lane's k-group
#pragma unroll
    for (int i = 0; i < 4; ++i) {
      af[i]  = *(const bf16x8*)((const char*)As +
                 (size_t)(wm * 64 + i * 16 + (l & 15)) * 64 + koff);
      bfr[i] = *(const bf16x8*)((const char*)Bs +
                 (size_t)(wn * 64 + i * 16 + (l & 15)) * 64 + koff);
    }
#pragma unroll
    for (int i = 0; i < 4; ++i)
#pragma unroll
      for (int j = 0; j < 4; ++j)
        acc[i][j] = __builtin_amdgcn_mfma_f32_16x16x32_bf16(
            af[i], bfr[j], acc[i][j], 0, 0, 0);
    __syncthreads();
  }

  // epilogue: out = acc + (h - mu)*rsig*g + b
  float gv[4], bv[4];
  int cols[4];
#pragma unroll
  for (int j = 0; j < 4; ++j) {
    const int col = n0 + wn * 64 + j * 16 + (l & 15);
    cols[j] = col; gv[j] = g[col]; bv[j] = bvec[col];
  }
#pragma unroll
  for (int i = 0; i < 4; ++i) {
#pragma unroll
    for (int r = 0; r < 4; ++r) {
      const int row = m0 + wm * 64 + i * 16 + (l >> 4) * 4 + r;
      const float2 st = stats[row];
      const float* hrow = h + (size_t)row * INDIM;
      float* orow = out + (size_t)row * INDIM;
#pragma unroll
      for (int j = 0; j < 4; ++j) {
        const float lnv = (hrow[cols[j]] - st.x) * st.y * gv[j] + bv[j];
        orow[cols[j]] = acc[i][j][r] + lnv;
      }
    }
  }
}

extern "C" void kernel_launch(void* const* d_in, const int* in_sizes, int n_in,
                              void* d_out, int out_size, void* d_ws, size_t ws_size,
                              hipStream_t stream)
{
  const float* h    = (const float*)d_in[0];
  const float* Wy   = (const float*)d_in[1];
  const float* Wq   = (const float*)d_in[2];
  const float* Wk   = (const float*)d_in[3];
  const float* wb   = (const float*)d_in[4];
  const float* outw = (const float*)d_in[5];
  const float* lng  = (const float*)d_in[6];
  const float* lnb  = (const float*)d_in[7];
  float* out = (float*)d_out;

  char* ws = (char*)d_ws;
  __hip_bfloat16* ys  = (__hip_bfloat16*)ws;                       // 67,108,864 B
  __hip_bfloat16* wbf = (__hip_bfloat16*)(ws + 67108864);          //  2,097,152 B
  float2*       stats = (float2*)(ws + 67108864 + 2097152);        //    262,144 B

  cvt_bf16 <<<4096, 256, 0, stream>>>(outw, wbf, INDIM * INDIM);
  ln_stats <<<8192, 256, 0, stream>>>(h, stats);
  srwm_scan<<<512,  256, 0, stream>>>(h, Wy, Wq, Wk, wb, ys);
  gemm_ln  <<<dim3(256, 8), 256, 0, stream>>>(ys, wbf, h, stats, lng, lnb, out);
}